// Round 3
// baseline (14274.742 us; speedup 1.0000x reference)
//
#include <hip/hip_runtime.h>
#include <hip/hip_bf16.h>
#include <hip/hip_cooperative_groups.h>

namespace cg = cooperative_groups;

#define Bb 512
#define Ww 50
#define Tt 50
#define Hh 1024
#define Vv 1024
#define MVv 64
#define Ll 30
#define G4 4096
#define SOS_IDX 0
#define EOS_IDX 1
#define N_CVT 29
#define SLOT ((size_t)Bb * Hh)
// CPol aux bits on gfx950: bit0 = SC0, bit4 = SC1 -> 0x11 = device-coherent read
#define AUX_COH 17

typedef __bf16 bf16x8 __attribute__((ext_vector_type(8)));
typedef float f32x4 __attribute__((ext_vector_type(4)));
typedef __hip_bfloat16 bf16;

__device__ __forceinline__ float bf2f(bf16 x) { return __bfloat162float(x); }
__device__ __forceinline__ float sigm(float x) { return 1.0f / (1.0f + __expf(-x)); }
__device__ __forceinline__ float tanh_f(float x) { return 1.0f - 2.0f / (1.0f + __expf(2.0f * x)); }
__device__ __forceinline__ float bfbits2f(unsigned short s) {
    union { float f; unsigned u; } x; x.u = ((unsigned)s) << 16; return x.f;
}
// Device-coherent bf16 store: lands at IC (agent coherence point), no local L2 copy.
__device__ __forceinline__ void store_bf16_agent(bf16* p, float v) {
    union { bf16 b; unsigned short u; } cv; cv.b = __float2bfloat16(v);
    unsigned uu = cv.u;
    asm volatile("global_store_short %0, %1, off sc0 sc1 nt" :: "v"(p), "v"(uu) : "memory");
}

// ---------------- dtype detect: input_mask is all-ones ----------------
__global__ void detect_kernel(const unsigned* __restrict__ mask_words, unsigned* __restrict__ flag)
{
    if (threadIdx.x == 0 && blockIdx.x == 0)
        flag[0] = (mask_words[0] == 0x3F800000u) ? 1u : 0u;
}

// ---------------- batched convert: float arrays -> bf16 ws copies ----------------
struct CvtArgs {
    const void* src[N_CVT];
    bf16* dst[N_CVT];
    int n[N_CVT];
    int klog2[N_CVT];
};

__global__ __launch_bounds__(256) void convert_kernel(CvtArgs a, const unsigned* __restrict__ flag)
{
    int id = blockIdx.y;
    int n = a.n[id];
    int kl = a.klog2[id];
    int i0 = (blockIdx.x * 256 + threadIdx.x) * 8;
    if (i0 >= n) return;
    bf16* d = a.dst[id];
    bool f32 = flag[0] != 0;
    if (n >= 8) {
        int e = i0;
        int srcidx = e;
        if (kl) {
            int r = e >> kl;
            int k = e & ((1 << kl) - 1);
            srcidx = ((((r & 3) << 10) | (r >> 2)) << kl) | k;
        }
        if (f32) {
            const f32x4* s = (const f32x4*)((const float*)a.src[id] + srcidx);
            f32x4 v0 = s[0], v1 = s[1];
            union { bf16 b[8]; uint4 v4; } o;
#pragma unroll
            for (int j = 0; j < 4; ++j) o.b[j] = __float2bfloat16(v0[j]);
#pragma unroll
            for (int j = 0; j < 4; ++j) o.b[4 + j] = __float2bfloat16(v1[j]);
            *(uint4*)(void*)(d + e) = o.v4;
        } else {
            uint4 v = *(const uint4*)((const unsigned short*)a.src[id] + srcidx);
            *(uint4*)(void*)(d + e) = v;
        }
    } else {
        if (f32) d[0] = __float2bfloat16(((const float*)a.src[id])[0]);
        else ((unsigned short*)d)[0] = ((const unsigned short*)a.src[id])[0];
    }
}

// ---------------- precompute: fused bias vectors (gate-interleaved) + attn const ----------------
__global__ void precompute_kernel(
    const bf16* __restrict__ set_Whh, const bf16* __restrict__ set_bih,
    const bf16* __restrict__ set_bhh, const bf16* __restrict__ set_h0,
    const bf16* __restrict__ gen_Wih, const bf16* __restrict__ gen_bih,
    const bf16* __restrict__ gen_bhh, const bf16* __restrict__ gen_x0,
    const bf16* __restrict__ menc_bih, const bf16* __restrict__ menc_bhh,
    const bf16* __restrict__ dec_bih, const bf16* __restrict__ dec_bhh,
    const bf16* __restrict__ dec_outb, const bf16* __restrict__ attn_w,
    const bf16* __restrict__ attn_b,
    float* encbias, float* genbias, float* mencbias, float* decbias,
    float* decoutb_f, float* c0dot)
{
    int tid = threadIdx.x;
    int o = blockIdx.x * 256 + tid;
    int pr = ((o & 1023) << 2) | (o >> 10);
    int sec = blockIdx.y;
    if (sec == 0) {
        float acc = bf2f(set_bih[o]) + bf2f(set_bhh[o]);
        const bf16* wr = set_Whh + (size_t)pr * Hh;
        for (int k = 0; k < Hh; ++k) acc += bf2f(set_h0[k]) * bf2f(wr[k]);
        encbias[pr] = acc;
    } else if (sec == 1) {
        float acc = bf2f(gen_bih[o]) + bf2f(gen_bhh[o]);
        const bf16* wr = gen_Wih + (size_t)pr * MVv;
        for (int k = 0; k < MVv; ++k) acc += bf2f(gen_x0[k]) * bf2f(wr[k]);
        genbias[pr] = acc;
    } else if (sec == 2) {
        mencbias[pr] = bf2f(menc_bih[o]) + bf2f(menc_bhh[o]);
    } else if (sec == 3) {
        decbias[pr] = bf2f(dec_bih[o]) + bf2f(dec_bhh[o]);
    } else if (sec == 4) {
        if (o < Vv) decoutb_f[o] = bf2f(dec_outb[o]);
    } else {
        if (blockIdx.x == 0) {
            __shared__ float red[256];
            float p = 0.f;
            for (int k = tid; k < Hh; k += 256) p += bf2f(set_h0[k]) * bf2f(attn_w[k]);
            red[tid] = p;
            __syncthreads();
            for (int s = 128; s > 0; s >>= 1) {
                if (tid < s) red[tid] += red[tid + s];
                __syncthreads();
            }
            if (tid == 0) c0dot[0] = red[0] + bf2f(attn_b[0]);
        }
    }
}

// ---------------- attention pooling ----------------
__global__ __launch_bounds__(256) void attention_kernel(
    const int* __restrict__ input_var, const bf16* __restrict__ input_mask,
    const bf16* __restrict__ embedding, const bf16* __restrict__ attn_w,
    const float* __restrict__ c0dot, bf16* __restrict__ r_out, float* __restrict__ m_init)
{
    int b = blockIdx.x;
    int tid = threadIdx.x;
    __shared__ float red[256];
    __shared__ float aw_s;
    const int* iv = input_var + b * Ww;
    float racc[4] = {0.f, 0.f, 0.f, 0.f};
    float wv[4];
#pragma unroll
    for (int j = 0; j < 4; ++j) wv[j] = bf2f(attn_w[Hh + tid + j * 256]);
    float cd = c0dot[0];
    for (int w = 0; w < Ww; ++w) {
        const bf16* e = embedding + (size_t)iv[w] * Hh;
        float ev[4], p = 0.f;
#pragma unroll
        for (int j = 0; j < 4; ++j) {
            ev[j] = bf2f(e[tid + j * 256]);
            p += ev[j] * wv[j];
        }
        red[tid] = p;
        __syncthreads();
        if (tid < 128) red[tid] += red[tid + 128];
        __syncthreads();
        if (tid < 64) {
            float v = red[tid] + red[tid + 64];
#pragma unroll
            for (int off = 32; off > 0; off >>= 1) v += __shfl_down(v, off);
            if (tid == 0) aw_s = sigm(v + cd) * bf2f(input_mask[w * Bb + b]);
        }
        __syncthreads();
        float aw = aw_s;
#pragma unroll
        for (int j = 0; j < 4; ++j) racc[j] += aw * ev[j];
    }
#pragma unroll
    for (int j = 0; j < 4; ++j)
        r_out[(size_t)b * Hh + tid + j * 256] = __float2bfloat16(racc[j]);
    if (tid == 0) m_init[b] = 1.0f;
}

// ---------------- state init ----------------
__global__ void init_state_kernel(const bf16* __restrict__ h0, const bf16* __restrict__ c0,
                                  float* __restrict__ h, float* __restrict__ c, bf16* __restrict__ hb)
{
    int i = blockIdx.x * blockDim.x + threadIdx.x;
    if (i >= Bb * Hh) return;
    int k = i & (Hh - 1);
    h[i] = bf2f(h0[k]);
    c[i] = bf2f(c0[k]);
    hb[i] = h0[k];
}

// ---------------- async global->LDS staging of a 64x64 bf16 weight chunk ----------------
__device__ __forceinline__ void stage_chunk(const bf16* __restrict__ W, int K, int n0, int kc,
                                            char* lbase, int tid)
{
#pragma unroll
    for (int it = 0; it < 2; ++it) {
        int gidx = it * 256 + tid;
        int rowi = gidx >> 3;
        int s8 = (gidx & 7) << 3;
        int ksrc = s8 ^ ((rowi & 7) << 3);
        const bf16* gp = W + (size_t)(n0 + rowi) * K + kc + ksrc;
        __builtin_amdgcn_global_load_lds(
            (const __attribute__((address_space(1))) unsigned*)gp,
            (__attribute__((address_space(3))) unsigned*)(lbase + gidx * 16), 16, 0, 0);
    }
}

// A-chunk staging; AUX=AUX_COH makes the read device-coherent (bypass stale L1/L2).
template<int AUX>
__device__ __forceinline__ void stage_chunkA(const bf16* __restrict__ A, size_t ro0, size_t ro1,
                                             int kc, char* lbase, int tid)
{
    int r0 = tid >> 3, c8 = tid & 7;
    {
        const bf16* gp = A + ro0 + kc + ((c8 ^ (r0 & 7)) << 3);
        __builtin_amdgcn_global_load_lds(
            (const __attribute__((address_space(1))) unsigned*)gp,
            (__attribute__((address_space(3))) unsigned*)(lbase + tid * 16), 16, 0, AUX);
    }
    {
        const bf16* gp = A + ro1 + kc + ((c8 ^ (r0 & 7)) << 3);   // (32+r0)&7 == r0&7
        __builtin_amdgcn_global_load_lds(
            (const __attribute__((address_space(1))) unsigned*)gp,
            (__attribute__((address_space(3))) unsigned*)(lbase + (256 + tid) * 16), 16, 0, AUX);
    }
}

// ---------------- LSTM step tile ----------------
// AUX1/AUX2: cache policy for A1/A2 staging. AGT: hb_out stores device-coherent (IC).
template<int AUX1, int AUX2, bool AGT>
__device__ __forceinline__ void lstm_tile(
    char* smem, int tid,
    const bf16* __restrict__ A1, const int* __restrict__ idx1, int lda1, int K1,
    const bf16* __restrict__ W1,
    const bf16* __restrict__ A2, int K2, const bf16* __restrict__ W2,
    const float* __restrict__ biasI, const float* __restrict__ mask,
    float* __restrict__ h, float* __restrict__ c, bf16* __restrict__ hb_out,
    int n0, int m0)
{
    int lane = tid & 63, wv = tid >> 6;
    int q = lane >> 4, ln = lane & 15;
    int mr0 = m0 + (tid >> 3), mr1 = mr0 + 32;
    size_t a1r0 = idx1 ? (size_t)idx1[mr0] * Hh : (size_t)mr0 * (size_t)lda1;
    size_t a1r1 = idx1 ? (size_t)idx1[mr1] * Hh : (size_t)mr1 * (size_t)lda1;
    size_t a2r0 = (size_t)mr0 * (size_t)K2, a2r1 = (size_t)mr1 * (size_t)K2;
    int nch1 = K1 >> 6, nch = nch1 + (K2 >> 6);
    f32x4 acc[4] = {};

    stage_chunk(W1, K1, n0, 0, smem, tid);
    stage_chunkA<AUX1>(A1, a1r0, a1r1, 0, smem + 16384, tid);
    __syncthreads();

    for (int ch = 0; ch < nch; ++ch) {
        int buf = ch & 1, nx = ch + 1;
        if (nx < nch) {
            char* bB = smem + (buf ^ 1) * 8192;
            char* bA = smem + 16384 + (buf ^ 1) * 8192;
            if (nx < nch1) {
                stage_chunk(W1, K1, n0, nx * 64, bB, tid);
                stage_chunkA<AUX1>(A1, a1r0, a1r1, nx * 64, bA, tid);
            } else {
                stage_chunk(W2, K2, n0, (nx - nch1) * 64, bB, tid);
                stage_chunkA<AUX2>(A2, a2r0, a2r1, (nx - nch1) * 64, bA, tid);
            }
        }
#pragma unroll
        for (int ks = 0; ks < 2; ++ks) {
            int rowb = wv * 16 + ln;
            int koff = ks * 32 + q * 8;
            bf16x8 bfr = *(const bf16x8*)(smem + buf * 8192 + rowb * 128 +
                                          ((koff ^ ((rowb & 7) * 8)) * 2));
#pragma unroll
            for (int ms = 0; ms < 4; ++ms) {
                int rowa = ms * 16 + ln;
                bf16x8 afr = *(const bf16x8*)(smem + 16384 + buf * 8192 + rowa * 128 +
                                              ((koff ^ ((rowa & 7) * 8)) * 2));
                acc[ms] = __builtin_amdgcn_mfma_f32_16x16x32_bf16(afr, bfr, acc[ms], 0, 0, 0);
            }
        }
        __syncthreads();
    }

    // LSTM epilogue via LDS bounce: gt[64 rows][64 gate-cols] fp32
    float* gt = (float*)smem;
    float bv = biasI[n0 + wv * 16 + ln];
#pragma unroll
    for (int ms = 0; ms < 4; ++ms)
#pragma unroll
        for (int r = 0; r < 4; ++r)
            gt[(ms * 16 + q * 4 + r) * 64 + wv * 16 + ln] = acc[ms][r] + bv;
    __syncthreads();
#pragma unroll
    for (int i = 0; i < 4; ++i) {
        int idx = i * 256 + tid;
        int rowl = idx >> 4, uu = idx & 15;
        f32x4 gq = *(const f32x4*)(gt + rowl * 64 + uu * 4);
        int rowg = m0 + rowl;
        size_t six = (size_t)rowg * Hh + (n0 >> 2) + uu;
        float cold = c[six];
        float iv = sigm(gq[0]), fv = sigm(gq[1]);
        float gv = tanh_f(gq[2]), ov = sigm(gq[3]);
        float cn = fv * cold + iv * gv;
        float hn = ov * tanh_f(cn);
        if (mask) {
            float mt = mask[rowg];
            float hold = h[six];
            hn = mt * hn + (1.f - mt) * hold;
            cn = mt * cn + (1.f - mt) * cold;
        }
        h[six] = hn;
        c[six] = cn;
        if constexpr (AGT) store_bf16_agent(hb_out + six, hn);
        else hb_out[six] = __float2bfloat16(hn);
    }
    __syncthreads();   // gt reads done before caller re-stages into smem
}

// ---------------- generator output (fallback: fp32 h row from global) ----------------
__device__ __forceinline__ void gen_out_row(
    const float* __restrict__ hrow, const bf16* __restrict__ outW,
    const bf16* __restrict__ outb, bf16* __restrict__ message_t,
    float* __restrict__ msgmask_t, float* __restrict__ m, int b, int lane)
{
    float acc = bf2f(outb[lane]);
    const bf16* wr = outW + (size_t)lane * Hh;
    for (int k = 0; k < Hh; k += 8) {
        bf16x8 wv = *(const bf16x8*)(wr + k);
        f32x4 h0 = *(const f32x4*)(hrow + k);
        f32x4 h1 = *(const f32x4*)(hrow + k + 4);
        acc += h0[0] * (float)wv[0] + h0[1] * (float)wv[1] + h0[2] * (float)wv[2] + h0[3] * (float)wv[3]
             + h1[0] * (float)wv[4] + h1[1] * (float)wv[5] + h1[2] * (float)wv[6] + h1[3] * (float)wv[7];
    }
    float mx = acc;
#pragma unroll
    for (int off = 32; off > 0; off >>= 1) mx = fmaxf(mx, __shfl_xor(mx, off));
    float e = __expf(acc - mx);
    float s = e;
#pragma unroll
    for (int off = 32; off > 0; off >>= 1) s += __shfl_xor(s, off);
    float p = e / s;
    message_t[b * MVv + lane] = __float2bfloat16(p);
    float peos = __shfl(p, EOS_IDX);
    if (lane == 0) {
        float mo = m[b];
        msgmask_t[b] = mo;
        m[b] = mo * (1.f - peos);
    }
}

// ---------------- persistent cooperative generator loop ----------------
// Chain (write-once slots) + IC-coherent stores/loads: no address is re-read after
// being rewritten within the kernel, so no reliance on cross-XCD L2 coherence.
__global__ __launch_bounds__(256) void gen_coop_kernel(
    bf16* chain, const bf16* W, const float* biasI,
    float* h, float* c,
    const bf16* outW, const bf16* outb,
    bf16* message, float* msgmask, float* m)
{
    cg::grid_group grid = cg::this_grid();
    __shared__ __align__(16) char smem[32768];
    __shared__ float hs[Hh];
    int tid = threadIdx.x;
    int n0 = blockIdx.x * 64, m0 = blockIdx.y * 64;
    int bb = blockIdx.x + 64 * blockIdx.y;   // batch row owned for gen_out
    for (int t = 0; t < Ll; ++t) {
        bf16* Ain  = chain + (size_t)t * SLOT;
        bf16* Aout = chain + (size_t)(t + 1) * SLOT;
        lstm_tile<AUX_COH, 0, true>(smem, tid, Ain, nullptr, Hh, Hh, W,
                                    nullptr, 0, nullptr, biasI, nullptr,
                                    h, c, Aout, n0, m0);
        __threadfence();
        grid.sync();
        if (tid < 64) {
            // stage Aout row bb into LDS via device-coherent loads (this block
            // part-wrote the row's cache lines -> must bypass local caches)
            const unsigned* hp = (const unsigned*)(Aout + (size_t)bb * Hh);
#pragma unroll
            for (int j = 0; j < 8; ++j) {
                unsigned u = __hip_atomic_load(hp + tid + 64 * j, __ATOMIC_RELAXED,
                                               __HIP_MEMORY_SCOPE_AGENT);
                hs[(tid + 64 * j) * 2]     = bfbits2f((unsigned short)(u & 0xFFFFu));
                hs[(tid + 64 * j) * 2 + 1] = bfbits2f((unsigned short)(u >> 16));
            }
            float acc = bf2f(outb[tid]);
            const bf16* wr = outW + (size_t)tid * Hh;
            for (int k = 0; k < Hh; k += 8) {
                bf16x8 wv = *(const bf16x8*)(wr + k);
#pragma unroll
                for (int j = 0; j < 8; ++j) acc += hs[k + j] * (float)wv[j];
            }
            float mx = acc;
#pragma unroll
            for (int off = 32; off > 0; off >>= 1) mx = fmaxf(mx, __shfl_xor(mx, off));
            float e = __expf(acc - mx);
            float s = e;
#pragma unroll
            for (int off = 32; off > 0; off >>= 1) s += __shfl_xor(s, off);
            float p = e / s;
            message[(size_t)t * Bb * MVv + bb * MVv + tid] = __float2bfloat16(p);
            float peos = __shfl(p, EOS_IDX);
            if (tid == 0) {
                float mo = m[bb];
                msgmask[t * Bb + bb] = mo;   // mask BEFORE update
                m[bb] = mo * (1.f - peos);
            }
        }
        // next iteration reads Aout (written pre-sync) and slot t+2 untouched so far
    }
}

// ---------------- persistent cooperative message-encoder loop ----------------
// chain base points at slot 19; uses slots 19..49 (final state in slot 49).
__global__ __launch_bounds__(256) void menc_coop_kernel(
    const bf16* message, const float* msgmask,
    bf16* chain, const bf16* Wih, const bf16* Whh, const float* biasI,
    float* h, float* c)
{
    cg::grid_group grid = cg::this_grid();
    __shared__ __align__(16) char smem[32768];
    int tid = threadIdx.x;
    int n0 = blockIdx.x * 64, m0 = blockIdx.y * 64;
    for (int t = 0; t < Ll; ++t) {
        bf16* Ain  = chain + (size_t)t * SLOT;
        bf16* Aout = chain + (size_t)(t + 1) * SLOT;
        lstm_tile<0, AUX_COH, true>(smem, tid, message + (size_t)t * Bb * MVv, nullptr, MVv, MVv,
                                    Wih, Ain, Hh, Whh, biasI, msgmask + t * Bb,
                                    h, c, Aout, n0, m0);
        __threadfence();
        grid.sync();
    }
}

// ---------------- persistent cooperative decoder loop ----------------
// Reads hb_init = chain slot 49 (menc final) at t=0; writes slot t each step.
__global__ __launch_bounds__(256) void dec_coop_kernel(
    const bf16* embedding, const int* target_var, bf16* chain,
    const bf16* Wih, const bf16* Whh, const float* biasI,
    float* h, float* c)
{
    cg::grid_group grid = cg::this_grid();
    __shared__ __align__(16) char smem[32768];
    int tid = threadIdx.x;
    int n0 = blockIdx.x * 64, m0 = blockIdx.y * 64;
    for (int t = 0; t < Tt; ++t) {
        const bf16* a1 = (t == 0) ? (embedding + (size_t)SOS_IDX * Hh) : embedding;
        const int* idxp = (t == 0) ? nullptr : (target_var + (size_t)(t - 1) * Bb);
        int lda1 = (t == 0) ? 0 : Hh;
        const bf16* a2 = (t == 0) ? (chain + (size_t)49 * SLOT) : (chain + (size_t)(t - 1) * SLOT);
        lstm_tile<0, AUX_COH, true>(smem, tid, a1, idxp, lda1, Hh, Wih, a2, Hh, Whh,
                                    biasI, nullptr, h, c, chain + (size_t)t * SLOT, n0, m0);
        __threadfence();
        grid.sync();
    }
}

// ---------------- fused step kernel (non-coop: enc step, projection, fallbacks) ----------------
__global__ __launch_bounds__(256) void step_kernel(
    const bf16* __restrict__ A1, const int* __restrict__ idx1, int lda1, int K1,
    const bf16* __restrict__ W1,
    const bf16* __restrict__ A2, int K2, const bf16* __restrict__ W2,
    const float* __restrict__ biasI,
    int mode, const float* __restrict__ mask,
    float* __restrict__ h, float* __restrict__ c, bf16* __restrict__ hb_out,
    void* __restrict__ outx, size_t obase, int ldo,
    const unsigned* __restrict__ fpflag)
{
    __shared__ __align__(16) char smem[32768];
    int tid = threadIdx.x;
    int n0 = blockIdx.x * 64, m0 = blockIdx.y * 64;

    if (mode == 1) {
        lstm_tile<0, 0, false>(smem, tid, A1, idx1, lda1, K1, W1, A2, K2, W2,
                               biasI, mask, h, c, hb_out, n0, m0);
        return;
    }

    // mode 0: GEMM + bias store
    int lane = tid & 63, wv = tid >> 6;
    int q = lane >> 4, ln = lane & 15;
    int mr0 = m0 + (tid >> 3), mr1 = mr0 + 32;
    size_t a1r0 = (size_t)mr0 * (size_t)lda1;
    size_t a1r1 = (size_t)mr1 * (size_t)lda1;
    int nch = K1 >> 6;
    f32x4 acc[4] = {};

    stage_chunk(W1, K1, n0, 0, smem, tid);
    stage_chunkA<0>(A1, a1r0, a1r1, 0, smem + 16384, tid);
    __syncthreads();

    for (int ch = 0; ch < nch; ++ch) {
        int buf = ch & 1, nx = ch + 1;
        if (nx < nch) {
            stage_chunk(W1, K1, n0, nx * 64, smem + (buf ^ 1) * 8192, tid);
            stage_chunkA<0>(A1, a1r0, a1r1, nx * 64, smem + 16384 + (buf ^ 1) * 8192, tid);
        }
#pragma unroll
        for (int ks = 0; ks < 2; ++ks) {
            int rowb = wv * 16 + ln;
            int koff = ks * 32 + q * 8;
            bf16x8 bfr = *(const bf16x8*)(smem + buf * 8192 + rowb * 128 +
                                          ((koff ^ ((rowb & 7) * 8)) * 2));
#pragma unroll
            for (int ms = 0; ms < 4; ++ms) {
                int rowa = ms * 16 + ln;
                bf16x8 afr = *(const bf16x8*)(smem + 16384 + buf * 8192 + rowa * 128 +
                                              ((koff ^ ((rowa & 7) * 8)) * 2));
                acc[ms] = __builtin_amdgcn_mfma_f32_16x16x32_bf16(afr, bfr, acc[ms], 0, 0, 0);
            }
        }
        __syncthreads();
    }

    bool f32o = fpflag && fpflag[0];
    int colr = n0 + wv * 16 + ln;
    float bv = biasI ? biasI[colr] : 0.f;
#pragma unroll
    for (int ms = 0; ms < 4; ++ms) {
#pragma unroll
        for (int r = 0; r < 4; ++r) {
            int rowr = m0 + ms * 16 + q * 4 + r;
            float v = acc[ms][r] + bv;
            size_t oi = obase + (size_t)rowr * ldo + colr;
            if (f32o) ((float*)outx)[oi] = v;
            else ((bf16*)outx)[oi] = __float2bfloat16(v);
        }
    }
}

// ---------------- generator output kernel (fallback path only) ----------------
__global__ __launch_bounds__(64) void gen_out_kernel(
    const float* __restrict__ h, const bf16* __restrict__ outW, const bf16* __restrict__ outb,
    bf16* __restrict__ message_t, float* __restrict__ msgmask_t, float* __restrict__ m)
{
    int b = blockIdx.x;
    int lane = threadIdx.x;
    gen_out_row(h + (size_t)b * Hh, outW, outb, message_t, msgmask_t, m, b, lane);
}

extern "C" void kernel_launch(void* const* d_in, const int* in_sizes, int n_in,
                              void* d_out, int out_size, void* d_ws, size_t ws_size,
                              hipStream_t stream)
{
    (void)in_sizes; (void)n_in; (void)out_size;
    const int* input_var  = (const int*)d_in[0];
    const int* target_var = (const int*)d_in[2];

    static int coop_cached = -1;
    if (coop_cached < 0) {
        int dev = 0, v = 0;
        hipGetDevice(&dev);
        if (hipDeviceGetAttribute(&v, hipDeviceAttributeCooperativeLaunch, dev) != hipSuccess) v = 0;
        coop_cached = v;
    }

    char* wsp = (char*)d_ws;
    size_t off = 0;
    auto alloc = [&](size_t bytes) -> void* {
        void* p = wsp + off;
        off += (bytes + 255) & ~(size_t)255;
        return p;
    };
    unsigned* flag  = (unsigned*)alloc(256);
    float* encbias  = (float*)alloc(G4 * 4);
    float* genbias  = (float*)alloc(G4 * 4);
    float* mencbias = (float*)alloc(G4 * 4);
    float* decbias  = (float*)alloc(G4 * 4);
    float* decoutb  = (float*)alloc(Vv * 4);
    float* c0dot    = (float*)alloc(256);
    float* m        = (float*)alloc(Bb * 4);
    float* h        = (float*)alloc(SLOT * 4);
    float* c        = (float*)alloc(SLOT * 4);
    bf16*  hbA      = (bf16*)alloc(SLOT * 2);
    bf16*  hbB      = (bf16*)alloc(SLOT * 2);
    bf16*  rb       = (bf16*)alloc(SLOT * 2);
    bf16*  message  = (bf16*)alloc((size_t)Ll * Bb * MVv * 2);
    float* msgmask  = (float*)alloc((size_t)Ll * Bb * 4);

    static const int cvt_in_idx[N_CVT] = {1, 4, 5, 6, 7, 8, 9, 10, 11, 12, 13, 14, 15,
                                          16, 17, 18, 19, 20, 21, 22, 23, 24, 25, 26,
                                          27, 28, 29, 30, 31};
    static const int cvt_n[N_CVT] = {
        Ww * Bb, Vv * Hh, 2 * Hh, 1,
        G4 * Hh, G4 * Hh, G4, G4, Hh, Hh,
        MVv, G4 * MVv, G4 * Hh, G4, G4, MVv * Hh, MVv,
        G4 * MVv, G4 * Hh, G4, G4, Hh, Hh,
        G4 * Hh, G4 * Hh, G4, G4, Vv * Hh, Vv };
    static const int cvt_kl[N_CVT] = {
        0, 0, 0, 0,
        10, 10, 0, 0, 0, 0,
        0, 6, 10, 0, 0, 0, 0,
        6, 10, 0, 0, 0, 0,
        10, 10, 0, 0, 0, 0 };
    CvtArgs ca;
    bf16* cp[N_CVT];
    for (int i = 0; i < N_CVT; ++i) {
        cp[i] = (bf16*)alloc((size_t)cvt_n[i] * 2);
        ca.src[i] = d_in[cvt_in_idx[i]];
        ca.dst[i] = cp[i];
        ca.n[i] = cvt_n[i];
        ca.klog2[i] = cvt_kl[i];
    }
    const bf16 *input_mask = cp[0], *embedding = cp[1], *attn_w = cp[2], *attn_b = cp[3],
               *set_Wih = cp[4], *set_Whh = cp[5], *set_bih = cp[6], *set_bhh = cp[7],
               *set_h0 = cp[8], *set_c0 = cp[9], *gen_x0 = cp[10], *gen_Wih = cp[11],
               *gen_Whh = cp[12], *gen_bih = cp[13], *gen_bhh = cp[14], *gen_outW = cp[15],
               *gen_outb = cp[16], *menc_Wih = cp[17], *menc_Whh = cp[18], *menc_bih = cp[19],
               *menc_bhh = cp[20], *menc_h0 = cp[21], *menc_c0 = cp[22], *dec_Wih = cp[23],
               *dec_Whh = cp[24], *dec_bih = cp[25], *dec_bhh = cp[26], *dec_outW = cp[27],
               *dec_outb = cp[28];

    // 50-slot h_t chain (also the decoder h history for the batched projection)
    size_t need_hb_all = (size_t)Tt * SLOT * 2 + 256;
    bf16* hb_all = (off + need_hb_all <= ws_size) ? (bf16*)alloc(need_hb_all) : nullptr;
    bool use_chain = hb_all != nullptr;
    bool coop = (coop_cached != 0) && use_chain;

    detect_kernel<<<1, 64, 0, stream>>>((const unsigned*)d_in[1], flag);
    convert_kernel<<<dim3(2048, N_CVT), 256, 0, stream>>>(ca, flag);

    precompute_kernel<<<dim3(16, 6), 256, 0, stream>>>(
        set_Whh, set_bih, set_bhh, set_h0,
        gen_Wih, gen_bih, gen_bhh, gen_x0,
        menc_bih, menc_bhh, dec_bih, dec_bhh,
        dec_outb, attn_w, attn_b,
        encbias, genbias, mencbias, decbias, decoutb, c0dot);

    attention_kernel<<<Bb, 256, 0, stream>>>(input_var, input_mask, embedding, attn_w, c0dot, rb, m);

    dim3 sgrid(64, 8);   // x = n-tiles, y = m-tiles

    bf16* slot0 = use_chain ? hb_all : hbA;
    init_state_kernel<<<2048, 256, 0, stream>>>(set_h0, set_c0, h, c, slot0);

    // set encoder LSTM step -> chain slot 0 (or hbA when no chain)
    step_kernel<<<sgrid, 256, 0, stream>>>(rb, nullptr, Hh, Hh, set_Wih,
                                           nullptr, 0, nullptr, encbias, 1, nullptr,
                                           h, c, slot0, nullptr, 0, 0, nullptr);

    // ---------- per-step fallback helpers (chain-addressed when available) ----------
    auto run_gen_steps = [&]() {
        for (int t = 0; t < Ll; ++t) {
            bf16* Ain  = use_chain ? hb_all + (size_t)t * SLOT       : ((t & 1) ? hbB : hbA);
            bf16* Aout = use_chain ? hb_all + (size_t)(t + 1) * SLOT : ((t & 1) ? hbA : hbB);
            step_kernel<<<sgrid, 256, 0, stream>>>(Ain, nullptr, Hh, Hh, gen_Whh,
                                                   nullptr, 0, nullptr, genbias, 1, nullptr,
                                                   h, c, Aout, nullptr, 0, 0, nullptr);
            gen_out_kernel<<<Bb, 64, 0, stream>>>(h, gen_outW, gen_outb,
                                                  message + (size_t)t * Bb * MVv, msgmask + t * Bb, m);
        }
    };
    auto run_menc_steps = [&](bf16* base) {
        for (int t = 0; t < Ll; ++t) {
            bf16* Ain  = use_chain ? base + (size_t)t * SLOT       : ((t & 1) ? hbB : hbA);
            bf16* Aout = use_chain ? base + (size_t)(t + 1) * SLOT : ((t & 1) ? hbA : hbB);
            step_kernel<<<sgrid, 256, 0, stream>>>(message + (size_t)t * Bb * MVv, nullptr, MVv, MVv,
                                                   menc_Wih, Ain, Hh, menc_Whh, mencbias, 1,
                                                   msgmask + t * Bb, h, c, Aout, nullptr, 0, 0, nullptr);
        }
    };
    auto run_dec_steps = [&](const bf16* hinit) {
        for (int t = 0; t < Tt; ++t) {
            const bf16* a1 = (t == 0) ? (embedding + (size_t)SOS_IDX * Hh) : embedding;
            const int* idxp = (t == 0) ? nullptr : (target_var + (size_t)(t - 1) * Bb);
            int lda1 = (t == 0) ? 0 : Hh;
            const bf16* a2 = (t == 0) ? hinit : (hb_all + (size_t)(t - 1) * SLOT);
            step_kernel<<<sgrid, 256, 0, stream>>>(a1, idxp, lda1, Hh, dec_Wih,
                                                   a2, Hh, dec_Whh, decbias, 1, nullptr,
                                                   h, c, hb_all + (size_t)t * SLOT,
                                                   nullptr, 0, 0, nullptr);
        }
    };

    // ---------------- generator ----------------
    if (coop) {
        bf16* chainp = hb_all; const bf16* Wp = gen_Whh; const float* bp = genbias;
        float* hp = h; float* cpn = c;
        const bf16* oW = gen_outW; const bf16* ob = gen_outb;
        bf16* msg = message; float* mm = msgmask; float* mp = m;
        void* ga[] = {&chainp, &Wp, &bp, &hp, &cpn, &oW, &ob, &msg, &mm, &mp};
        if (hipLaunchCooperativeKernel(gen_coop_kernel, sgrid, dim3(256), ga, 0, stream)
            != hipSuccess) {
            coop = false;
            run_gen_steps();
        }
    } else {
        run_gen_steps();
    }

    // ---------------- message encoder (chain slots 19..49) ----------------
    bf16* menc_base = use_chain ? hb_all + (size_t)19 * SLOT : hbA;
    init_state_kernel<<<2048, 256, 0, stream>>>(menc_h0, menc_c0, h, c, menc_base);
    if (coop) {
        const bf16* msg = message; const float* mm = msgmask;
        bf16* chainp = menc_base;
        const bf16* Wi = menc_Wih; const bf16* Wh = menc_Whh; const float* bp = mencbias;
        float* hp = h; float* cpn = c;
        void* ga[] = {&msg, &mm, &chainp, &Wi, &Wh, &bp, &hp, &cpn};
        if (hipLaunchCooperativeKernel(menc_coop_kernel, sgrid, dim3(256), ga, 0, stream)
            != hipSuccess) {
            coop = false;
            run_menc_steps(menc_base);
        }
    } else {
        run_menc_steps(menc_base);
    }
    // menc final state: chain slot 49 (coop or chain fallback), else hbA (Ll even)
    const bf16* menc_final = use_chain ? hb_all + (size_t)49 * SLOT : hbA;

    // ---------------- decoder ----------------
    if (use_chain) {
        if (coop) {
            const bf16* emb = embedding; const int* tv = target_var;
            bf16* chainp = hb_all;
            const bf16* Wi = dec_Wih; const bf16* Wh = dec_Whh; const float* bp = decbias;
            float* hp = h; float* cpn = c;
            void* ga[] = {&emb, &tv, &chainp, &Wi, &Wh, &bp, &hp, &cpn};
            if (hipLaunchCooperativeKernel(dec_coop_kernel, sgrid, dim3(256), ga, 0, stream)
                != hipSuccess) {
                run_dec_steps(menc_final);
            }
        } else {
            run_dec_steps(menc_final);
        }
        // batched decoder output projection: M = 50*512 rows
        step_kernel<<<dim3(16, (Tt * Bb) / 64), 256, 0, stream>>>(
            hb_all, nullptr, Hh, Hh, dec_outW,
            nullptr, 0, nullptr, decoutb, 0, nullptr,
            nullptr, nullptr, nullptr, d_out, 0, Vv, flag);
    } else {
        // no chain: per-step decoder + per-step projection (r1 path)
        bf16* cur = hbA; bf16* nxt = hbB;
        for (int t = 0; t < Tt; ++t) {
            const bf16* a1 = (t == 0) ? (embedding + (size_t)SOS_IDX * Hh) : embedding;
            const int* idxp = (t == 0) ? nullptr : (target_var + (size_t)(t - 1) * Bb);
            int lda1 = (t == 0) ? 0 : Hh;
            step_kernel<<<sgrid, 256, 0, stream>>>(a1, idxp, lda1, Hh, dec_Wih,
                                                   cur, Hh, dec_Whh, decbias, 1, nullptr,
                                                   h, c, nxt, nullptr, 0, 0, nullptr);
            step_kernel<<<dim3(16, 8), 256, 0, stream>>>(nxt, nullptr, Hh, Hh, dec_outW,
                                                         nullptr, 0, nullptr, decoutb, 0, nullptr,
                                                         nullptr, nullptr, nullptr,
                                                         d_out, (size_t)t * Bb * Vv, Vv, flag);
            bf16* tmp = cur; cur = nxt; nxt = tmp;
        }
    }
}

// Round 5
// 2669.461 us; speedup vs baseline: 5.3474x; 5.3474x over previous
//
#include <hip/hip_runtime.h>
#include <hip/hip_bf16.h>

#define Bb 512
#define Ww 50
#define Tt 50
#define Hh 1024
#define Vv 1024
#define MVv 64
#define Ll 30
#define G4 4096
#define SOS_IDX 0
#define EOS_IDX 1
#define N_CVT 29

typedef __bf16 bf16x8 __attribute__((ext_vector_type(8)));
typedef float f32x4 __attribute__((ext_vector_type(4)));
typedef __hip_bfloat16 bf16;

__device__ __forceinline__ float bf2f(bf16 x) { return __bfloat162float(x); }
__device__ __forceinline__ float sigm(float x) { return 1.0f / (1.0f + __expf(-x)); }
__device__ __forceinline__ float tanh_f(float x) { return 1.0f - 2.0f / (1.0f + __expf(2.0f * x)); }

// ---------------- dtype detect: input_mask is all-ones ----------------
__global__ void detect_kernel(const unsigned* __restrict__ mask_words, unsigned* __restrict__ flag)
{
    if (threadIdx.x == 0 && blockIdx.x == 0)
        flag[0] = (mask_words[0] == 0x3F800000u) ? 1u : 0u;
}

// ---------------- batched convert: float arrays -> bf16 ws copies (vectorized) ----------------
// klog2 != 0 => gate-interleave row permutation: dst row r' = 4u+g of src row g*1024+u.
// 8 elements per thread stay within one source row (K >= 64, i0 multiple of 8).
struct CvtArgs {
    const void* src[N_CVT];
    bf16* dst[N_CVT];
    int n[N_CVT];
    int klog2[N_CVT];
};

__global__ __launch_bounds__(256) void convert_kernel(CvtArgs a, const unsigned* __restrict__ flag)
{
    int id = blockIdx.y;
    int n = a.n[id];
    int kl = a.klog2[id];
    int i0 = (blockIdx.x * 256 + threadIdx.x) * 8;
    if (i0 >= n) return;
    bf16* d = a.dst[id];
    bool f32 = flag[0] != 0;
    if (n >= 8) {
        int e = i0;
        int srcidx = e;
        if (kl) {
            int r = e >> kl;
            int k = e & ((1 << kl) - 1);
            srcidx = ((((r & 3) << 10) | (r >> 2)) << kl) | k;
        }
        if (f32) {
            const f32x4* s = (const f32x4*)((const float*)a.src[id] + srcidx);
            f32x4 v0 = s[0], v1 = s[1];
            union { bf16 b[8]; uint4 v4; } o;
#pragma unroll
            for (int j = 0; j < 4; ++j) o.b[j] = __float2bfloat16(v0[j]);
#pragma unroll
            for (int j = 0; j < 4; ++j) o.b[4 + j] = __float2bfloat16(v1[j]);
            *(uint4*)(void*)(d + e) = o.v4;
        } else {
            uint4 v = *(const uint4*)((const unsigned short*)a.src[id] + srcidx);
            *(uint4*)(void*)(d + e) = v;
        }
    } else {
        if (f32) d[0] = __float2bfloat16(((const float*)a.src[id])[0]);
        else ((unsigned short*)d)[0] = ((const unsigned short*)a.src[id])[0];
    }
}

// ---------------- precompute: fused bias vectors (gate-interleaved) + attn const ----------------
__global__ void precompute_kernel(
    const bf16* __restrict__ set_Whh, const bf16* __restrict__ set_bih,
    const bf16* __restrict__ set_bhh, const bf16* __restrict__ set_h0,
    const bf16* __restrict__ gen_Wih, const bf16* __restrict__ gen_bih,
    const bf16* __restrict__ gen_bhh, const bf16* __restrict__ gen_x0,
    const bf16* __restrict__ menc_bih, const bf16* __restrict__ menc_bhh,
    const bf16* __restrict__ dec_bih, const bf16* __restrict__ dec_bhh,
    const bf16* __restrict__ dec_outb, const bf16* __restrict__ attn_w,
    const bf16* __restrict__ attn_b,
    float* encbias, float* genbias, float* mencbias, float* decbias,
    float* decoutb_f, float* c0dot)
{
    int tid = threadIdx.x;
    int o = blockIdx.x * 256 + tid;
    int pr = ((o & 1023) << 2) | (o >> 10);
    int sec = blockIdx.y;
    if (sec == 0) {
        float acc = bf2f(set_bih[o]) + bf2f(set_bhh[o]);
        const bf16* wr = set_Whh + (size_t)pr * Hh;
        for (int k = 0; k < Hh; ++k) acc += bf2f(set_h0[k]) * bf2f(wr[k]);
        encbias[pr] = acc;
    } else if (sec == 1) {
        float acc = bf2f(gen_bih[o]) + bf2f(gen_bhh[o]);
        const bf16* wr = gen_Wih + (size_t)pr * MVv;
        for (int k = 0; k < MVv; ++k) acc += bf2f(gen_x0[k]) * bf2f(wr[k]);
        genbias[pr] = acc;
    } else if (sec == 2) {
        mencbias[pr] = bf2f(menc_bih[o]) + bf2f(menc_bhh[o]);
    } else if (sec == 3) {
        decbias[pr] = bf2f(dec_bih[o]) + bf2f(dec_bhh[o]);
    } else if (sec == 4) {
        if (o < Vv) decoutb_f[o] = bf2f(dec_outb[o]);
    } else {
        if (blockIdx.x == 0) {
            __shared__ float red[256];
            float p = 0.f;
            for (int k = tid; k < Hh; k += 256) p += bf2f(set_h0[k]) * bf2f(attn_w[k]);
            red[tid] = p;
            __syncthreads();
            for (int s = 128; s > 0; s >>= 1) {
                if (tid < s) red[tid] += red[tid + s];
                __syncthreads();
            }
            if (tid == 0) c0dot[0] = red[0] + bf2f(attn_b[0]);
        }
    }
}

// ---------------- attention pooling ----------------
__global__ __launch_bounds__(256) void attention_kernel(
    const int* __restrict__ input_var, const bf16* __restrict__ input_mask,
    const bf16* __restrict__ embedding, const bf16* __restrict__ attn_w,
    const float* __restrict__ c0dot, bf16* __restrict__ r_out, float* __restrict__ m_init)
{
    int b = blockIdx.x;
    int tid = threadIdx.x;
    __shared__ float red[256];
    __shared__ float aw_s;
    const int* iv = input_var + b * Ww;
    float racc[4] = {0.f, 0.f, 0.f, 0.f};
    float wv[4];
#pragma unroll
    for (int j = 0; j < 4; ++j) wv[j] = bf2f(attn_w[Hh + tid + j * 256]);
    float cd = c0dot[0];
    for (int w = 0; w < Ww; ++w) {
        const bf16* e = embedding + (size_t)iv[w] * Hh;
        float ev[4], p = 0.f;
#pragma unroll
        for (int j = 0; j < 4; ++j) {
            ev[j] = bf2f(e[tid + j * 256]);
            p += ev[j] * wv[j];
        }
        red[tid] = p;
        __syncthreads();
        if (tid < 128) red[tid] += red[tid + 128];
        __syncthreads();
        if (tid < 64) {
            float v = red[tid] + red[tid + 64];
#pragma unroll
            for (int off = 32; off > 0; off >>= 1) v += __shfl_down(v, off);
            if (tid == 0) aw_s = sigm(v + cd) * bf2f(input_mask[w * Bb + b]);
        }
        __syncthreads();
        float aw = aw_s;
#pragma unroll
        for (int j = 0; j < 4; ++j) racc[j] += aw * ev[j];
    }
#pragma unroll
    for (int j = 0; j < 4; ++j)
        r_out[(size_t)b * Hh + tid + j * 256] = __float2bfloat16(racc[j]);
    if (tid == 0) m_init[b] = 1.0f;
}

// ---------------- state init ----------------
__global__ void init_state_kernel(const bf16* __restrict__ h0, const bf16* __restrict__ c0,
                                  float* __restrict__ h, float* __restrict__ c, bf16* __restrict__ hb)
{
    int i = blockIdx.x * blockDim.x + threadIdx.x;
    if (i >= Bb * Hh) return;
    int k = i & (Hh - 1);
    h[i] = bf2f(h0[k]);
    c[i] = bf2f(c0[k]);
    hb[i] = h0[k];
}

// ---------------- async global->LDS staging of a 64x64 bf16 weight chunk ----------------
// LDS layout: row*128B + slot*2B, slot granule s8 holds source k = s8 ^ ((row&7)*8)
// (XOR swizzle so ds_read_b128 of fragments is bank-balanced). Wave-uniform base + lane*16.
__device__ __forceinline__ void stage_chunk(const bf16* __restrict__ W, int K, int n0, int kc,
                                            char* lbase, int tid)
{
#pragma unroll
    for (int it = 0; it < 2; ++it) {
        int gidx = it * 256 + tid;            // granule of 8 bf16 = 16B
        int rowi = gidx >> 3;
        int s8 = (gidx & 7) << 3;
        int ksrc = s8 ^ ((rowi & 7) << 3);
        const bf16* gp = W + (size_t)(n0 + rowi) * K + kc + ksrc;
        __builtin_amdgcn_global_load_lds(
            (const __attribute__((address_space(1))) unsigned*)gp,
            (__attribute__((address_space(3))) unsigned*)(lbase + gidx * 16), 16, 0, 0);
    }
}

// ---------------- async global->LDS staging of a 64x64 bf16 A-chunk (gather-capable) ---------
__device__ __forceinline__ void stage_chunkA(const bf16* __restrict__ A, size_t ro0, size_t ro1,
                                             int kc, char* lbase, int tid)
{
    int r0 = tid >> 3, c8 = tid & 7;
    {
        const bf16* gp = A + ro0 + kc + ((c8 ^ (r0 & 7)) << 3);
        __builtin_amdgcn_global_load_lds(
            (const __attribute__((address_space(1))) unsigned*)gp,
            (__attribute__((address_space(3))) unsigned*)(lbase + tid * 16), 16, 0, 0);
    }
    {
        const bf16* gp = A + ro1 + kc + ((c8 ^ (r0 & 7)) << 3);   // (32+r0)&7 == r0&7
        __builtin_amdgcn_global_load_lds(
            (const __attribute__((address_space(1))) unsigned*)gp,
            (__attribute__((address_space(3))) unsigned*)(lbase + (256 + tid) * 16), 16, 0, 0);
    }
}

// ---------------- shared GEMM K-loop ----------------
// Tile 64(M)x64(N), 4 waves each owning a 32x32 quadrant (wm=wv>>1, wn=wv&1) built from
// 2x2 16x16x32 MFMA tiles -> 8 ds_read_b128 + 8 MFMA per chunk per wave.
// Depth-2 prefetch: 3 A-slots + 3 B-slots; per-chunk sync = counted `s_waitcnt vmcnt(4)`
// (4 staging instrs/wave/chunk; ch+2 stays in flight) + raw s_barrier.
// lgkmcnt(0) in the barrier asm: guarantees no ds_read is outstanding when a wave crosses
// the barrier (slot is rewritten 3 chunks later by global_load_lds; without the drain a
// compiler-sunk MFMA+lgkm-wait could let the read cross — guide rule #18 class hazard).
// vmcnt counts are safe against hoisted loads (extras are newer -> over-wait only).
// smem: [0, 24K) B slots, [24K, 48K) A slots.
__device__ __forceinline__ void gemm_k_loop(
    char* smem, int tid,
    const bf16* __restrict__ A1, size_t a1r0, size_t a1r1, int K1,
    const bf16* __restrict__ W1,
    const bf16* __restrict__ A2, size_t a2r0, size_t a2r1, int K2,
    const bf16* __restrict__ W2,
    int n0, f32x4 (&acc)[2][2])
{
    int lane = tid & 63, wv = tid >> 6;
    int q = lane >> 4, ln = lane & 15;
    int wm = wv >> 1, wn = wv & 1;
    int nch1 = K1 >> 6, nch = nch1 + (K2 >> 6);

    auto stageC = [&](int cidx, int slot) {
        char* bB = smem + slot * 8192;
        char* bA = smem + 24576 + slot * 8192;
        if (cidx < nch1) {
            stage_chunk(W1, K1, n0, cidx * 64, bB, tid);
            stage_chunkA(A1, a1r0, a1r1, cidx * 64, bA, tid);
        } else {
            stage_chunk(W2, K2, n0, (cidx - nch1) * 64, bB, tid);
            stage_chunkA(A2, a2r0, a2r1, (cidx - nch1) * 64, bA, tid);
        }
    };

    stageC(0, 0);
    stageC(1, 1);                     // nch >= 16 for every caller
    asm volatile("s_waitcnt vmcnt(4) lgkmcnt(0)\n\ts_barrier" ::: "memory");

    int slot = 0;
    int ra = wm * 32 + ln;            // (ra+16)&7 == ra&7, swizzle term reused
    int rb = wn * 32 + ln;
    int sa = (ra & 7) * 8, sb = (rb & 7) * 8;
    for (int ch = 0; ch < nch; ++ch) {
        if (ch + 2 < nch) {
            int s2 = slot + 2; if (s2 >= 3) s2 -= 3;
            stageC(ch + 2, s2);
        }
        const char* bB = smem + slot * 8192;
        const char* bA = smem + 24576 + slot * 8192;
#pragma unroll
        for (int ks = 0; ks < 2; ++ks) {
            int koff = ks * 32 + q * 8;
            bf16x8 af0 = *(const bf16x8*)(bA + ra * 128 + ((koff ^ sa) * 2));
            bf16x8 af1 = *(const bf16x8*)(bA + (ra + 16) * 128 + ((koff ^ sa) * 2));
            bf16x8 bf0 = *(const bf16x8*)(bB + rb * 128 + ((koff ^ sb) * 2));
            bf16x8 bf1 = *(const bf16x8*)(bB + (rb + 16) * 128 + ((koff ^ sb) * 2));
            acc[0][0] = __builtin_amdgcn_mfma_f32_16x16x32_bf16(af0, bf0, acc[0][0], 0, 0, 0);
            acc[0][1] = __builtin_amdgcn_mfma_f32_16x16x32_bf16(af0, bf1, acc[0][1], 0, 0, 0);
            acc[1][0] = __builtin_amdgcn_mfma_f32_16x16x32_bf16(af1, bf0, acc[1][0], 0, 0, 0);
            acc[1][1] = __builtin_amdgcn_mfma_f32_16x16x32_bf16(af1, bf1, acc[1][1], 0, 0, 0);
        }
        if (ch + 1 < nch) {
            if (ch + 2 < nch) asm volatile("s_waitcnt vmcnt(4) lgkmcnt(0)\n\ts_barrier" ::: "memory");
            else              asm volatile("s_waitcnt vmcnt(0) lgkmcnt(0)\n\ts_barrier" ::: "memory");
        }
        slot = (slot + 1 == 3) ? 0 : slot + 1;
    }
    __syncthreads();   // all waves done reading LDS before epilogue reuses it
}

// ---------------- fused step kernel ----------------
// mode 1: N=4096 gate-interleaved -> LSTM epilogue updates h,c and writes hb_out (bf16).
// mode 0: plain store (+bias) to outx at obase, dtype per fpflag.
__global__ __launch_bounds__(256) void step_kernel(
    const bf16* __restrict__ A1, const int* __restrict__ idx1, int lda1, int K1,
    const bf16* __restrict__ W1,
    const bf16* __restrict__ A2, int K2, const bf16* __restrict__ W2,
    const float* __restrict__ biasI,
    int mode, const float* __restrict__ mask,
    float* __restrict__ h, float* __restrict__ c, bf16* __restrict__ hb_out,
    void* __restrict__ outx, size_t obase, int ldo,
    const unsigned* __restrict__ fpflag)
{
    // [0,24K) B slots x3, [24K,48K) A slots x3; epilogue gt reuses [0,16K)
    __shared__ __align__(16) char smem[49152];
    int tid = threadIdx.x;
    int lane = tid & 63, wv = tid >> 6;
    int q = lane >> 4, ln = lane & 15;
    int wm = wv >> 1, wn = wv & 1;
    int n0 = blockIdx.x * 64, m0 = blockIdx.y * 64;

    int mr0 = m0 + (tid >> 3), mr1 = mr0 + 32;
    size_t a1r0 = idx1 ? (size_t)idx1[mr0] * Hh : (size_t)mr0 * (size_t)lda1;
    size_t a1r1 = idx1 ? (size_t)idx1[mr1] * Hh : (size_t)mr1 * (size_t)lda1;
    size_t a2r0 = (size_t)mr0 * (size_t)K2, a2r1 = (size_t)mr1 * (size_t)K2;

    f32x4 acc[2][2] = {};
    gemm_k_loop(smem, tid, A1, a1r0, a1r1, K1, W1, A2, a2r0, a2r1, K2, W2, n0, acc);

    if (mode == 1) {
        // LSTM epilogue via LDS bounce: gt[64 rows][64 gate-cols] fp32
        float* gt = (float*)smem;
        int colb = wn * 32 + ln;
        float bv0 = biasI[n0 + colb];
        float bv1 = biasI[n0 + colb + 16];
#pragma unroll
        for (int ms = 0; ms < 2; ++ms)
#pragma unroll
            for (int r = 0; r < 4; ++r) {
                int row = wm * 32 + ms * 16 + q * 4 + r;
                gt[row * 64 + colb]      = acc[ms][0][r] + bv0;
                gt[row * 64 + colb + 16] = acc[ms][1][r] + bv1;
            }
        __syncthreads();
#pragma unroll
        for (int i = 0; i < 4; ++i) {
            int idx = i * 256 + tid;
            int rowl = idx >> 4, uu = idx & 15;
            f32x4 gq = *(const f32x4*)(gt + rowl * 64 + uu * 4);
            int rowg = m0 + rowl;
            size_t six = (size_t)rowg * Hh + (n0 >> 2) + uu;
            float cold = c[six];
            float iv = sigm(gq[0]), fv = sigm(gq[1]);
            float gv = tanh_f(gq[2]), ov = sigm(gq[3]);
            float cn = fv * cold + iv * gv;
            float hn = ov * tanh_f(cn);
            if (mask) {
                float mt = mask[rowg];
                float hold = h[six];
                hn = mt * hn + (1.f - mt) * hold;
                cn = mt * cn + (1.f - mt) * cold;
            }
            h[six] = hn;
            c[six] = cn;
            hb_out[six] = __float2bfloat16(hn);
        }
    } else {
        bool f32o = fpflag && fpflag[0];
        int colr = n0 + wn * 32 + ln;
        float bva = biasI ? biasI[colr] : 0.f;
        float bvb = biasI ? biasI[colr + 16] : 0.f;
#pragma unroll
        for (int ms = 0; ms < 2; ++ms) {
#pragma unroll
            for (int r = 0; r < 4; ++r) {
                int rowr = m0 + wm * 32 + ms * 16 + q * 4 + r;
                size_t oi = obase + (size_t)rowr * ldo + colr;
                float v0 = acc[ms][0][r] + bva;
                float v1 = acc[ms][1][r] + bvb;
                if (f32o) {
                    ((float*)outx)[oi] = v0;
                    ((float*)outx)[oi + 16] = v1;
                } else {
                    ((bf16*)outx)[oi] = __float2bfloat16(v0);
                    ((bf16*)outx)[oi + 16] = __float2bfloat16(v1);
                }
            }
        }
    }
}

// ---------------- generator output: softmax + mask update ----------------
__global__ __launch_bounds__(64) void gen_out_kernel(
    const float* __restrict__ h, const bf16* __restrict__ outW, const bf16* __restrict__ outb,
    bf16* __restrict__ message_t, float* __restrict__ msgmask_t, float* __restrict__ m)
{
    int b = blockIdx.x;
    int lane = threadIdx.x;
    __shared__ float hs[Hh];
    for (int k = lane; k < Hh; k += 64) hs[k] = h[(size_t)b * Hh + k];
    __syncthreads();
    float acc = bf2f(outb[lane]);
    const bf16* wr = outW + (size_t)lane * Hh;
    for (int k = 0; k < Hh; k += 8) {
        bf16x8 wv = *(const bf16x8*)(wr + k);
#pragma unroll
        for (int j = 0; j < 8; ++j) acc += hs[k + j] * (float)wv[j];
    }
    float mx = acc;
#pragma unroll
    for (int off = 32; off > 0; off >>= 1) mx = fmaxf(mx, __shfl_xor(mx, off));
    float e = __expf(acc - mx);
    float s = e;
#pragma unroll
    for (int off = 32; off > 0; off >>= 1) s += __shfl_xor(s, off);
    float p = e / s;
    message_t[b * MVv + lane] = __float2bfloat16(p);
    float peos = __shfl(p, EOS_IDX);
    if (lane == 0) {
        float mo = m[b];
        msgmask_t[b] = mo;           // mask BEFORE update (matches scan output)
        m[b] = mo * (1.f - peos);
    }
}

extern "C" void kernel_launch(void* const* d_in, const int* in_sizes, int n_in,
                              void* d_out, int out_size, void* d_ws, size_t ws_size,
                              hipStream_t stream)
{
    (void)in_sizes; (void)n_in; (void)out_size;
    const int* input_var  = (const int*)d_in[0];
    const int* target_var = (const int*)d_in[2];

    char* wsp = (char*)d_ws;
    size_t off = 0;
    auto alloc = [&](size_t bytes) -> void* {
        void* p = wsp + off;
        off += (bytes + 255) & ~(size_t)255;
        return p;
    };
    unsigned* flag  = (unsigned*)alloc(256);
    float* encbias  = (float*)alloc(G4 * 4);
    float* genbias  = (float*)alloc(G4 * 4);
    float* mencbias = (float*)alloc(G4 * 4);
    float* decbias  = (float*)alloc(G4 * 4);
    float* decoutb  = (float*)alloc(Vv * 4);
    float* c0dot    = (float*)alloc(256);
    float* m        = (float*)alloc(Bb * 4);
    float* h        = (float*)alloc((size_t)Bb * Hh * 4);
    float* c        = (float*)alloc((size_t)Bb * Hh * 4);
    bf16*  hbA      = (bf16*)alloc((size_t)Bb * Hh * 2);
    bf16*  hbB      = (bf16*)alloc((size_t)Bb * Hh * 2);
    bf16*  rb       = (bf16*)alloc((size_t)Bb * Hh * 2);
    bf16*  message  = (bf16*)alloc((size_t)Ll * Bb * MVv * 2);
    float* msgmask  = (float*)alloc((size_t)Ll * Bb * 4);

    // bf16 copies; weight matrices gate-interleaved (klog2 = log2 of row length)
    static const int cvt_in_idx[N_CVT] = {1, 4, 5, 6, 7, 8, 9, 10, 11, 12, 13, 14, 15,
                                          16, 17, 18, 19, 20, 21, 22, 23, 24, 25, 26,
                                          27, 28, 29, 30, 31};
    static const int cvt_n[N_CVT] = {
        Ww * Bb, Vv * Hh, 2 * Hh, 1,
        G4 * Hh, G4 * Hh, G4, G4, Hh, Hh,
        MVv, G4 * MVv, G4 * Hh, G4, G4, MVv * Hh, MVv,
        G4 * MVv, G4 * Hh, G4, G4, Hh, Hh,
        G4 * Hh, G4 * Hh, G4, G4, Vv * Hh, Vv };
    static const int cvt_kl[N_CVT] = {
        0, 0, 0, 0,
        10, 10, 0, 0, 0, 0,
        0, 6, 10, 0, 0, 0, 0,
        6, 10, 0, 0, 0, 0,
        10, 10, 0, 0, 0, 0 };
    CvtArgs ca;
    bf16* cp[N_CVT];
    for (int i = 0; i < N_CVT; ++i) {
        cp[i] = (bf16*)alloc((size_t)cvt_n[i] * 2);
        ca.src[i] = d_in[cvt_in_idx[i]];
        ca.dst[i] = cp[i];
        ca.n[i] = cvt_n[i];
        ca.klog2[i] = cvt_kl[i];
    }
    const bf16 *input_mask = cp[0], *embedding = cp[1], *attn_w = cp[2], *attn_b = cp[3],
               *set_Wih = cp[4], *set_Whh = cp[5], *set_bih = cp[6], *set_bhh = cp[7],
               *set_h0 = cp[8], *set_c0 = cp[9], *gen_x0 = cp[10], *gen_Wih = cp[11],
               *gen_Whh = cp[12], *gen_bih = cp[13], *gen_bhh = cp[14], *gen_outW = cp[15],
               *gen_outb = cp[16], *menc_Wih = cp[17], *menc_Whh = cp[18], *menc_bih = cp[19],
               *menc_bhh = cp[20], *menc_h0 = cp[21], *menc_c0 = cp[22], *dec_Wih = cp[23],
               *dec_Whh = cp[24], *dec_bih = cp[25], *dec_bhh = cp[26], *dec_outW = cp[27],
               *dec_outb = cp[28];

    // h_t history for batched decoder projection, only if workspace allows
    size_t need_hb_all = (size_t)Tt * Bb * Hh * 2 + 256;
    bf16* hb_all = (off + need_hb_all <= ws_size) ? (bf16*)alloc(need_hb_all) : nullptr;

    detect_kernel<<<1, 64, 0, stream>>>((const unsigned*)d_in[1], flag);
    convert_kernel<<<dim3(2048, N_CVT), 256, 0, stream>>>(ca, flag);

    precompute_kernel<<<dim3(16, 6), 256, 0, stream>>>(
        set_Whh, set_bih, set_bhh, set_h0,
        gen_Wih, gen_bih, gen_bhh, gen_x0,
        menc_bih, menc_bhh, dec_bih, dec_bhh,
        dec_outb, attn_w, attn_b,
        encbias, genbias, mencbias, decbias, decoutb, c0dot);

    attention_kernel<<<Bb, 256, 0, stream>>>(input_var, input_mask, embedding, attn_w, c0dot, rb, m);
    init_state_kernel<<<2048, 256, 0, stream>>>(set_h0, set_c0, h, c, hbA);

    bf16* cur = hbA;
    bf16* nxt = hbB;
    dim3 sgrid(64, 8);   // x = n-tiles (XCD-local weight slices), y = m-tiles

    // set encoder LSTM step
    step_kernel<<<sgrid, 256, 0, stream>>>(rb, nullptr, Hh, Hh, set_Wih,
                                           nullptr, 0, nullptr, encbias, 1, nullptr,
                                           h, c, cur, nullptr, 0, 0, nullptr);

    // generator loop
    for (int t = 0; t < Ll; ++t) {
        step_kernel<<<sgrid, 256, 0, stream>>>(cur, nullptr, Hh, Hh, gen_Whh,
                                               nullptr, 0, nullptr, genbias, 1, nullptr,
                                               h, c, nxt, nullptr, 0, 0, nullptr);
        gen_out_kernel<<<Bb, 64, 0, stream>>>(h, gen_outW, gen_outb,
                                              message + (size_t)t * Bb * MVv, msgmask + t * Bb, m);
        bf16* tmp = cur; cur = nxt; nxt = tmp;
    }

    // message encoder loop
    init_state_kernel<<<2048, 256, 0, stream>>>(menc_h0, menc_c0, h, c, cur);
    for (int t = 0; t < Ll; ++t) {
        step_kernel<<<sgrid, 256, 0, stream>>>(message + (size_t)t * Bb * MVv, nullptr, MVv, MVv, menc_Wih,
                                               cur, Hh, menc_Whh, mencbias, 1, msgmask + t * Bb,
                                               h, c, nxt, nullptr, 0, 0, nullptr);
        bf16* tmp = cur; cur = nxt; nxt = tmp;
    }

    // decoder loop
    for (int t = 0; t < Tt; ++t) {
        const bf16* a1 = (t == 0) ? (embedding + (size_t)SOS_IDX * Hh) : embedding;
        const int* idxp = (t == 0) ? nullptr : (target_var + (size_t)(t - 1) * Bb);
        int lda1 = (t == 0) ? 0 : Hh;
        const bf16* a2 = (t == 0) ? cur : (hb_all ? hb_all + (size_t)(t - 1) * Bb * Hh : cur);
        bf16* hbo = hb_all ? hb_all + (size_t)t * Bb * Hh : nxt;
        step_kernel<<<sgrid, 256, 0, stream>>>(a1, idxp, lda1, Hh, dec_Wih,
                                               a2, Hh, dec_Whh, decbias, 1, nullptr,
                                               h, c, hbo, nullptr, 0, 0, nullptr);
        if (!hb_all) {
            step_kernel<<<dim3(16, 8), 256, 0, stream>>>(nxt, nullptr, Hh, Hh, dec_outW,
                                                         nullptr, 0, nullptr, decoutb, 0, nullptr,
                                                         nullptr, nullptr, nullptr,
                                                         d_out, (size_t)t * Bb * Vv, Vv, flag);
            bf16* tmp = cur; cur = nxt; nxt = tmp;
        }
    }
    if (hb_all) {
        // batched decoder output projection: M = 50*512 rows
        step_kernel<<<dim3(16, (Tt * Bb) / 64), 256, 0, stream>>>(
            hb_all, nullptr, Hh, Hh, dec_outW,
            nullptr, 0, nullptr, decoutb, 0, nullptr,
            nullptr, nullptr, nullptr, d_out, 0, Vv, flag);
    }
}